// Round 2
// baseline (309.880 us; speedup 1.0000x reference)
//
#include <hip/hip_runtime.h>
#include <hip/hip_bf16.h>
#include <math.h>

#define N_TOK 4096
#define D_MODEL 1024
#define NHEAD 8
#define DKQ 16
#define DVH 64
#define QGW 80   // DK+DV columns per head
#define QGN 640  // H * 80

// ---------------------------------------------------------------------------
// GEMM: C = A(MxK) * B(KxN), all fp32. BM=128 BN=64 BK=16, 256 thr, 8x4/thr.
// Dual-B: blockIdx.x < ntiles_n -> (B0,C0) else (B1,C1). Pass B1=B0 for single.
// ---------------------------------------------------------------------------
__global__ __launch_bounds__(256) void gemm_dual(
    const float* __restrict__ A,
    const float* __restrict__ B0, float* __restrict__ C0,
    const float* __restrict__ B1, float* __restrict__ C1,
    int M, int Nb, int K, int ntiles_n)
{
    __shared__ float As[16][128];
    __shared__ float Bs[16][65];

    int tid = threadIdx.x;
    int bnt = blockIdx.x;
    const float* B = B0;
    float* C = C0;
    if (bnt >= ntiles_n) { B = B1; C = C1; bnt -= ntiles_n; }
    int bm = blockIdx.y * 128;
    int bn = bnt * 64;

    int tx = tid & 15;        // 0..15 along N
    int ty = tid >> 4;        // 0..15 along M
    int arow = tid >> 1;      // 0..127
    int akc  = (tid & 1) * 8; // 0 or 8
    int bkr  = tid >> 4;      // 0..15
    int bcol = (tid & 15) * 4;

    float acc[8][4] = {};

    for (int k0 = 0; k0 < K; k0 += 16) {
        float4 a0 = *(const float4*)(A + (size_t)(bm + arow) * K + k0 + akc);
        float4 a1 = *(const float4*)(A + (size_t)(bm + arow) * K + k0 + akc + 4);
        float4 b0 = *(const float4*)(B + (size_t)(k0 + bkr) * Nb + bn + bcol);

        As[akc + 0][arow] = a0.x; As[akc + 1][arow] = a0.y;
        As[akc + 2][arow] = a0.z; As[akc + 3][arow] = a0.w;
        As[akc + 4][arow] = a1.x; As[akc + 5][arow] = a1.y;
        As[akc + 6][arow] = a1.z; As[akc + 7][arow] = a1.w;
        Bs[bkr][bcol + 0] = b0.x; Bs[bkr][bcol + 1] = b0.y;
        Bs[bkr][bcol + 2] = b0.z; Bs[bkr][bcol + 3] = b0.w;
        __syncthreads();

        #pragma unroll
        for (int kk = 0; kk < 16; ++kk) {
            float a[8], b[4];
            #pragma unroll
            for (int i = 0; i < 8; ++i) a[i] = As[kk][ty * 8 + i];
            #pragma unroll
            for (int j = 0; j < 4; ++j) b[j] = Bs[kk][tx * 4 + j];
            #pragma unroll
            for (int i = 0; i < 8; ++i)
                #pragma unroll
                for (int j = 0; j < 4; ++j)
                    acc[i][j] += a[i] * b[j];
        }
        __syncthreads();
    }

    #pragma unroll
    for (int i = 0; i < 8; ++i) {
        float4 st = make_float4(acc[i][0], acc[i][1], acc[i][2], acc[i][3]);
        *(float4*)(C + (size_t)(bm + ty * 8 + i) * Nb + bn + tx * 4) = st;
    }
}

// ---------------------------------------------------------------------------
// Prep: one 64-thread wave per (h, n). Normalize q,k,v; gate = tanh(silu(g)).
// qg/kv layout: [n][h*80 + c]  (c<16 -> q/k, c>=16 -> g/v)
// Outputs: Q,K: [h][n][16]; V,G: [h][n][64]
// ---------------------------------------------------------------------------
__global__ __launch_bounds__(64) void prep_kernel(
    const float* __restrict__ qg, const float* __restrict__ kv,
    float* __restrict__ Q, float* __restrict__ Ko,
    float* __restrict__ V, float* __restrict__ G)
{
    int bid = blockIdx.x;          // h*N + n
    int h = bid >> 12;             // /4096
    int n = bid & (N_TOK - 1);
    int lane = threadIdx.x;

    const float* qgrow = qg + (size_t)n * QGN + h * QGW;
    const float* kvrow = kv + (size_t)n * QGN + h * QGW;

    // v (64) and g (64)
    float v = kvrow[DKQ + lane];
    float g = qgrow[DKQ + lane];
    float s = v * v;
    #pragma unroll
    for (int off = 32; off; off >>= 1) s += __shfl_xor(s, off);
    float vn = v / fmaxf(sqrtf(s), 1e-12f);
    V[((size_t)h * N_TOK + n) * DVH + lane] = vn;
    float sg = g / (1.f + expf(-g));        // silu
    G[((size_t)h * N_TOK + n) * DVH + lane] = tanhf(sg);

    // q, k (16 each) on lanes 0..15
    if (lane < DKQ) {
        float q = qgrow[lane];
        float k = kvrow[lane];
        float sq = q * q, sk = k * k;
        #pragma unroll
        for (int off = 8; off; off >>= 1) {
            sq += __shfl_xor(sq, off);
            sk += __shfl_xor(sk, off);
        }
        Q [((size_t)h * N_TOK + n) * DKQ + lane] = q / fmaxf(sqrtf(sq), 1e-12f);
        Ko[((size_t)h * N_TOK + n) * DKQ + lane] = k / fmaxf(sqrtf(sk), 1e-12f);
    }
}

// ---------------------------------------------------------------------------
// Windowed attention + norm/gate epilogue. One 64-thread wave per (h, i).
// Y layout: [i][h*64 + dv]  (ready for the output projection)
// ---------------------------------------------------------------------------
__global__ __launch_bounds__(64) void attn_kernel(
    const float* __restrict__ Q, const float* __restrict__ Ko,
    const float* __restrict__ V, const float* __restrict__ G,
    const float* __restrict__ log_window, const float* __restrict__ log_r,
    const float* __restrict__ log_hscale, float* __restrict__ Y)
{
    int bid = blockIdx.x;          // h*N + i
    int h = bid >> 12;
    int i = bid & (N_TOK - 1);
    int lane = threadIdx.x;

    float w  = expf(log_window[h]) + 1.f;
    float r  = expf(log_r[h]) + 1.f;
    float hs = expf(log_hscale[h]);
    int dmax = min(i, (int)ceilf(w) - 1);   // d in [0, dmax], always d < w

    __shared__ float att[384];

    const float* qp = Q + ((size_t)h * N_TOK + i) * DKQ;
    float q[DKQ];
    #pragma unroll
    for (int c = 0; c < DKQ; ++c) q[c] = qp[c];

    const float PI = 3.14159265358979f;
    for (int d = lane; d <= dmax; d += 64) {
        const float* kp = Ko + ((size_t)h * N_TOK + (i - d)) * DKQ;
        float sim = 0.f;
        #pragma unroll
        for (int c = 0; c < DKQ; ++c) sim += q[c] * kp[c];
        float a = 1.f - r * (1.f - sim);
        a = fmaxf(a, 0.f);
        a = a * a;
        float soft = 0.5f * (cosf(PI * (float)d / w) + 1.f);
        att[d] = a * soft;
    }
    __syncthreads();

    int dv = lane;
    float aggr = 0.f;
    for (int d = 0; d <= dmax; ++d) {
        aggr += att[d] * V[((size_t)h * N_TOK + (i - d)) * DVH + dv];
    }

    float s = aggr * aggr;
    #pragma unroll
    for (int off = 32; off; off >>= 1) s += __shfl_xor(s, off);
    float norm = sqrtf(s);
    float scale = tanhf(norm) / fmaxf(norm, 1e-12f);

    float out = aggr * scale * G[((size_t)h * N_TOK + i) * DVH + dv] * hs;
    Y[(size_t)i * (NHEAD * DVH) + h * DVH + dv] = out;
}

// ---------------------------------------------------------------------------
extern "C" void kernel_launch(void* const* d_in, const int* in_sizes, int n_in,
                              void* d_out, int out_size, void* d_ws, size_t ws_size,
                              hipStream_t stream)
{
    const float* tokens     = (const float*)d_in[0];
    const float* w_qg       = (const float*)d_in[1];
    const float* w_kv       = (const float*)d_in[2];
    const float* w_out      = (const float*)d_in[3];
    const float* log_window = (const float*)d_in[4];
    const float* log_r      = (const float*)d_in[5];
    const float* log_hscale = (const float*)d_in[6];
    float* out = (float*)d_out;

    char* ws = (char*)d_ws;
    float* qg = (float*)ws; ws += (size_t)N_TOK * QGN * 4;           // 10.5 MB
    float* kv = (float*)ws; ws += (size_t)N_TOK * QGN * 4;           // 10.5 MB
    float* Q  = (float*)ws; ws += (size_t)NHEAD * N_TOK * DKQ * 4;   // 2 MB
    float* Ko = (float*)ws; ws += (size_t)NHEAD * N_TOK * DKQ * 4;   // 2 MB
    float* V  = (float*)ws; ws += (size_t)NHEAD * N_TOK * DVH * 4;   // 8 MB
    float* G  = (float*)ws; ws += (size_t)NHEAD * N_TOK * DVH * 4;   // 8 MB
    float* Y  = (float*)ws; ws += (size_t)N_TOK * NHEAD * DVH * 4;   // 8 MB

    // 1) qg = tokens @ w_qg, kv = tokens @ w_kv   (dual-B, 640 cols each)
    {
        dim3 grid(2 * (QGN / 64), N_TOK / 128);
        gemm_dual<<<grid, 256, 0, stream>>>(tokens, w_qg, qg, w_kv, kv,
                                            N_TOK, QGN, D_MODEL, QGN / 64);
    }
    // 2) normalize + gate
    prep_kernel<<<NHEAD * N_TOK, 64, 0, stream>>>(qg, kv, Q, Ko, V, G);
    // 3) windowed attention + epilogue
    attn_kernel<<<NHEAD * N_TOK, 64, 0, stream>>>(Q, Ko, V, G,
                                                  log_window, log_r, log_hscale, Y);
    // 4) out = Y @ w_out
    {
        dim3 grid(D_MODEL / 64, N_TOK / 128);
        gemm_dual<<<grid, 256, 0, stream>>>(Y, w_out, out, w_out, out,
                                            N_TOK, D_MODEL, 512, D_MODEL / 64);
    }
}

// Round 3
// 120.657 us; speedup vs baseline: 2.5683x; 2.5683x over previous
//
#include <hip/hip_runtime.h>
#include <hip/hip_bf16.h>
#include <math.h>

#define N_TOK 4096
#define D_MODEL 1024
#define NHEAD 8
#define DKQ 16
#define DVH 64
#define QGW 80   // DK+DV columns per head
#define QGN 640  // H * 80
#define HD  512  // H * DV

typedef __attribute__((ext_vector_type(8))) short short8;
typedef __attribute__((ext_vector_type(4))) float f32x4;

#define GLOAD_LDS16(gp, lp) \
  __builtin_amdgcn_global_load_lds((const __attribute__((address_space(1))) void*)(gp), \
                                   (__attribute__((address_space(3))) void*)(lp), 16, 0, 0)

// ---------------------------------------------------------------------------
// fp32 -> bf16 elementwise cast (4 elems/thread)
// ---------------------------------------------------------------------------
__global__ __launch_bounds__(256) void cast_bf16_kernel(
    const float* __restrict__ in, __hip_bfloat16* __restrict__ out, int n)
{
    int i = (blockIdx.x * 256 + threadIdx.x) * 4;
    if (i >= n) return;
    float4 v = *(const float4*)(in + i);
    __hip_bfloat16 o[4] = { __float2bfloat16(v.x), __float2bfloat16(v.y),
                            __float2bfloat16(v.z), __float2bfloat16(v.w) };
    *(ushort4*)(out + i) = *(const ushort4*)o;
}

// ---------------------------------------------------------------------------
// transpose + cast: in fp32 [R][C] -> out bf16 [C][R]
// ---------------------------------------------------------------------------
__global__ __launch_bounds__(256) void transpose_cast_kernel(
    const float* __restrict__ in, __hip_bfloat16* __restrict__ out, int R, int C)
{
    __shared__ float tile[32][33];
    int bx = blockIdx.x * 32;   // column base (input)
    int by = blockIdx.y * 32;   // row base (input)
    int x = bx + threadIdx.x;
    for (int j = threadIdx.y; j < 32; j += 8) {
        int y = by + j;
        if (y < R && x < C) tile[j][threadIdx.x] = in[(size_t)y * C + x];
    }
    __syncthreads();
    int xo = by + threadIdx.x;  // out column = input row
    for (int j = threadIdx.y; j < 32; j += 8) {
        int yo = bx + j;        // out row = input column
        if (yo < C && xo < R)
            out[(size_t)yo * R + xo] = __float2bfloat16(tile[threadIdx.x][j]);
    }
}

// ---------------------------------------------------------------------------
// bf16 MFMA GEMM (m97 structure): C(fp32 MxNb) = A(bf16 MxK) * Bt(bf16 NbxK)^T
// 128x128 tile, 4 waves, BK=32, global_load_lds staging, 16x16x32 MFMA.
// Dual-B: blockIdx.x >= ntiles_n -> (Bt1, C1).
// ---------------------------------------------------------------------------
__global__ __launch_bounds__(256) void gemm_mfma(
    const __hip_bfloat16* __restrict__ A,
    const __hip_bfloat16* __restrict__ Bt0, float* __restrict__ C0,
    const __hip_bfloat16* __restrict__ Bt1, float* __restrict__ C1,
    int Nb, int K, int ntiles_n)
{
    __shared__ __hip_bfloat16 As[128 * 32];
    __shared__ __hip_bfloat16 Bs[128 * 32];

    int t = threadIdx.x;
    int l = t & 63;
    int w = t >> 6;
    int wr = w >> 1, wc = w & 1;

    int bnt = blockIdx.x;
    const __hip_bfloat16* Bt = Bt0;
    float* C = C0;
    if (bnt >= ntiles_n) { Bt = Bt1; C = C1; bnt -= ntiles_n; }
    int bm = blockIdx.y * 128;
    int bn = bnt * 128;

    // staging: chunk c = (row<<2)|kchunk ; issue0 rows 0-63, issue1 rows 64-127
    int srow = t >> 2;
    int skc  = (t & 3) * 8;
    const __hip_bfloat16* ga0 = A + (size_t)(bm + srow) * K + skc;
    const __hip_bfloat16* ga1 = A + (size_t)(bm + 64 + srow) * K + skc;
    const __hip_bfloat16* gb0 = Bt + (size_t)(bn + srow) * K + skc;
    const __hip_bfloat16* gb1 = Bt + (size_t)(bn + 64 + srow) * K + skc;
    __hip_bfloat16* lA0 = &As[(t & ~63) * 8];
    __hip_bfloat16* lA1 = &As[2048 + (t & ~63) * 8];
    __hip_bfloat16* lB0 = &Bs[(t & ~63) * 8];
    __hip_bfloat16* lB1 = &Bs[2048 + (t & ~63) * 8];

    f32x4 acc[4][4] = {};

    int aro = (wr * 64 + (l & 15)) * 32 + (l >> 4) * 8;  // A frag base (elem)
    int bro = (wc * 64 + (l & 15)) * 32 + (l >> 4) * 8;  // B frag base (elem)

    for (int k0 = 0; k0 < K; k0 += 32) {
        GLOAD_LDS16(ga0 + k0, lA0);
        GLOAD_LDS16(ga1 + k0, lA1);
        GLOAD_LDS16(gb0 + k0, lB0);
        GLOAD_LDS16(gb1 + k0, lB1);
        __syncthreads();

        short8 af[4], bf[4];
        #pragma unroll
        for (int m = 0; m < 4; ++m) af[m] = *(const short8*)&As[aro + m * 16 * 32];
        #pragma unroll
        for (int n = 0; n < 4; ++n) bf[n] = *(const short8*)&Bs[bro + n * 16 * 32];

        #pragma unroll
        for (int m = 0; m < 4; ++m)
            #pragma unroll
            for (int n = 0; n < 4; ++n)
                acc[m][n] = __builtin_amdgcn_mfma_f32_16x16x32_bf16(
                                af[m], bf[n], acc[m][n], 0, 0, 0);
        __syncthreads();
    }

    // C/D layout: col = lane&15, row = (lane>>4)*4 + j
    int crow = bm + wr * 64 + (l >> 4) * 4;
    int ccol = bn + wc * 64 + (l & 15);
    #pragma unroll
    for (int m = 0; m < 4; ++m)
        #pragma unroll
        for (int n = 0; n < 4; ++n)
            #pragma unroll
            for (int j = 0; j < 4; ++j)
                C[(size_t)(crow + m * 16 + j) * Nb + ccol + n * 16] = acc[m][n][j];
}

// ---------------------------------------------------------------------------
// Prep: one 64-thread wave per (h, n). Normalize q,k,v; gate = tanh(silu(g)).
// ---------------------------------------------------------------------------
__global__ __launch_bounds__(64) void prep_kernel(
    const float* __restrict__ qg, const float* __restrict__ kv,
    float* __restrict__ Q, float* __restrict__ Ko,
    float* __restrict__ V, float* __restrict__ G)
{
    int bid = blockIdx.x;
    int h = bid >> 12;
    int n = bid & (N_TOK - 1);
    int lane = threadIdx.x;

    const float* qgrow = qg + (size_t)n * QGN + h * QGW;
    const float* kvrow = kv + (size_t)n * QGN + h * QGW;

    float v = kvrow[DKQ + lane];
    float g = qgrow[DKQ + lane];
    float s = v * v;
    #pragma unroll
    for (int off = 32; off; off >>= 1) s += __shfl_xor(s, off);
    float vn = v / fmaxf(sqrtf(s), 1e-12f);
    V[((size_t)h * N_TOK + n) * DVH + lane] = vn;
    float sg = g / (1.f + expf(-g));
    G[((size_t)h * N_TOK + n) * DVH + lane] = tanhf(sg);

    if (lane < DKQ) {
        float q = qgrow[lane];
        float k = kvrow[lane];
        float sq = q * q, sk = k * k;
        #pragma unroll
        for (int off = 8; off; off >>= 1) {
            sq += __shfl_xor(sq, off);
            sk += __shfl_xor(sk, off);
        }
        Q [((size_t)h * N_TOK + n) * DKQ + lane] = q / fmaxf(sqrtf(sq), 1e-12f);
        Ko[((size_t)h * N_TOK + n) * DKQ + lane] = k / fmaxf(sqrtf(sk), 1e-12f);
    }
}

// ---------------------------------------------------------------------------
// Windowed attention + norm/gate epilogue; Y written in bf16 [i][h*64+dv]
// ---------------------------------------------------------------------------
__global__ __launch_bounds__(64) void attn_kernel(
    const float* __restrict__ Q, const float* __restrict__ Ko,
    const float* __restrict__ V, const float* __restrict__ G,
    const float* __restrict__ log_window, const float* __restrict__ log_r,
    const float* __restrict__ log_hscale, __hip_bfloat16* __restrict__ Y)
{
    int bid = blockIdx.x;
    int h = bid >> 12;
    int i = bid & (N_TOK - 1);
    int lane = threadIdx.x;

    float w  = expf(log_window[h]) + 1.f;
    float r  = expf(log_r[h]) + 1.f;
    float hs = expf(log_hscale[h]);
    int dmax = min(i, (int)ceilf(w) - 1);

    __shared__ float att[384];

    const float* qp = Q + ((size_t)h * N_TOK + i) * DKQ;
    float q[DKQ];
    #pragma unroll
    for (int c = 0; c < DKQ; ++c) q[c] = qp[c];

    const float PI = 3.14159265358979f;
    for (int d = lane; d <= dmax; d += 64) {
        const float* kp = Ko + ((size_t)h * N_TOK + (i - d)) * DKQ;
        float sim = 0.f;
        #pragma unroll
        for (int c = 0; c < DKQ; ++c) sim += q[c] * kp[c];
        float a = 1.f - r * (1.f - sim);
        a = fmaxf(a, 0.f);
        a = a * a;
        float soft = 0.5f * (cosf(PI * (float)d / w) + 1.f);
        att[d] = a * soft;
    }
    __syncthreads();

    int dv = lane;
    float aggr = 0.f;
    for (int d = 0; d <= dmax; ++d) {
        aggr += att[d] * V[((size_t)h * N_TOK + (i - d)) * DVH + dv];
    }

    float s = aggr * aggr;
    #pragma unroll
    for (int off = 32; off; off >>= 1) s += __shfl_xor(s, off);
    float norm = sqrtf(s);
    float scale = tanhf(norm) / fmaxf(norm, 1e-12f);

    float outv = aggr * scale * G[((size_t)h * N_TOK + i) * DVH + dv] * hs;
    Y[(size_t)i * HD + h * DVH + dv] = __float2bfloat16(outv);
}

// ---------------------------------------------------------------------------
extern "C" void kernel_launch(void* const* d_in, const int* in_sizes, int n_in,
                              void* d_out, int out_size, void* d_ws, size_t ws_size,
                              hipStream_t stream)
{
    const float* tokens     = (const float*)d_in[0];
    const float* w_qg       = (const float*)d_in[1];
    const float* w_kv       = (const float*)d_in[2];
    const float* w_out      = (const float*)d_in[3];
    const float* log_window = (const float*)d_in[4];
    const float* log_r      = (const float*)d_in[5];
    const float* log_hscale = (const float*)d_in[6];
    float* out = (float*)d_out;

    char* ws = (char*)d_ws;
    float* qg = (float*)ws;            ws += (size_t)N_TOK * QGN * 4;     // 10.5 MB
    float* kv = (float*)ws;            ws += (size_t)N_TOK * QGN * 4;     // 10.5 MB
    float* Q  = (float*)ws;            ws += (size_t)NHEAD * N_TOK * DKQ * 4;
    float* Ko = (float*)ws;            ws += (size_t)NHEAD * N_TOK * DKQ * 4;
    float* V  = (float*)ws;            ws += (size_t)NHEAD * N_TOK * DVH * 4;
    float* G  = (float*)ws;            ws += (size_t)NHEAD * N_TOK * DVH * 4;
    __hip_bfloat16* tokB  = (__hip_bfloat16*)ws; ws += (size_t)N_TOK * D_MODEL * 2;  // 8 MB
    __hip_bfloat16* wqgT  = (__hip_bfloat16*)ws; ws += (size_t)QGN * D_MODEL * 2;    // 1.3 MB
    __hip_bfloat16* wkvT  = (__hip_bfloat16*)ws; ws += (size_t)QGN * D_MODEL * 2;    // 1.3 MB
    __hip_bfloat16* woutT = (__hip_bfloat16*)ws; ws += (size_t)D_MODEL * HD * 2;     // 1 MB
    __hip_bfloat16* Yb    = (__hip_bfloat16*)ws; ws += (size_t)N_TOK * HD * 2;       // 4 MB

    // 0) casts / transposes
    cast_bf16_kernel<<<(N_TOK * D_MODEL / 4 + 255) / 256, 256, 0, stream>>>(
        tokens, tokB, N_TOK * D_MODEL);
    {
        dim3 blk(32, 8);
        transpose_cast_kernel<<<dim3(QGN / 32, D_MODEL / 32), blk, 0, stream>>>(
            w_qg, wqgT, D_MODEL, QGN);
        transpose_cast_kernel<<<dim3(QGN / 32, D_MODEL / 32), blk, 0, stream>>>(
            w_kv, wkvT, D_MODEL, QGN);
        transpose_cast_kernel<<<dim3(D_MODEL / 32, HD / 32), blk, 0, stream>>>(
            w_out, woutT, HD, D_MODEL);
    }

    // 1) qg = tokens @ w_qg, kv = tokens @ w_kv  (dual-B MFMA GEMM)
    {
        dim3 grid(2 * (QGN / 128), N_TOK / 128);   // 10 x 32
        gemm_mfma<<<grid, 256, 0, stream>>>(tokB, wqgT, qg, wkvT, kv,
                                            QGN, D_MODEL, QGN / 128);
    }
    // 2) normalize + gate
    prep_kernel<<<NHEAD * N_TOK, 64, 0, stream>>>(qg, kv, Q, Ko, V, G);
    // 3) windowed attention + epilogue -> Yb (bf16)
    attn_kernel<<<NHEAD * N_TOK, 64, 0, stream>>>(Q, Ko, V, G,
                                                  log_window, log_r, log_hscale, Yb);
    // 4) out = Y @ w_out (single-B MFMA GEMM)
    {
        dim3 grid(D_MODEL / 128, N_TOK / 128);     // 8 x 32
        gemm_mfma<<<grid, 256, 0, stream>>>(Yb, woutT, out, woutT, out,
                                            D_MODEL, HD, D_MODEL / 128);
    }
}

// Round 4
// 118.150 us; speedup vs baseline: 2.6228x; 1.0212x over previous
//
#include <hip/hip_runtime.h>
#include <hip/hip_bf16.h>
#include <math.h>

#define N_TOK 4096
#define D_MODEL 1024
#define NHEAD 8
#define DKQ 16
#define DVH 64
#define QGW 80   // DK+DV columns per head
#define QGN 640  // H * 80
#define HD  512  // H * DV
#define TI  32   // attention: i-rows per block
#define DC  64   // attention: j-chunk width

typedef __attribute__((ext_vector_type(8))) short short8;
typedef __attribute__((ext_vector_type(4))) float f32x4;

#define GLOAD_LDS16(gp, lp) \
  __builtin_amdgcn_global_load_lds((const __attribute__((address_space(1))) void*)(gp), \
                                   (__attribute__((address_space(3))) void*)(lp), 16, 0, 0)

// ---------------------------------------------------------------------------
// fp32 -> bf16 elementwise cast (4 elems/thread)
// ---------------------------------------------------------------------------
__global__ __launch_bounds__(256) void cast_bf16_kernel(
    const float* __restrict__ in, __hip_bfloat16* __restrict__ out, int n)
{
    int i = (blockIdx.x * 256 + threadIdx.x) * 4;
    if (i >= n) return;
    float4 v = *(const float4*)(in + i);
    __hip_bfloat16 o[4] = { __float2bfloat16(v.x), __float2bfloat16(v.y),
                            __float2bfloat16(v.z), __float2bfloat16(v.w) };
    *(ushort4*)(out + i) = *(const ushort4*)o;
}

// ---------------------------------------------------------------------------
// transpose + cast: in fp32 [R][C] -> out bf16 [C][R]
// ---------------------------------------------------------------------------
__global__ __launch_bounds__(256) void transpose_cast_kernel(
    const float* __restrict__ in, __hip_bfloat16* __restrict__ out, int R, int C)
{
    __shared__ float tile[32][33];
    int bx = blockIdx.x * 32;
    int by = blockIdx.y * 32;
    int x = bx + threadIdx.x;
    for (int j = threadIdx.y; j < 32; j += 8) {
        int y = by + j;
        if (y < R && x < C) tile[j][threadIdx.x] = in[(size_t)y * C + x];
    }
    __syncthreads();
    int xo = by + threadIdx.x;
    for (int j = threadIdx.y; j < 32; j += 8) {
        int yo = bx + j;
        if (yo < C && xo < R)
            out[(size_t)yo * R + xo] = __float2bfloat16(tile[threadIdx.x][j]);
    }
}

// ---------------------------------------------------------------------------
// bf16 MFMA GEMM (m97 structure): C(fp32 MxNb) = A(bf16 MxK) * Bt(bf16 NbxK)^T
// ---------------------------------------------------------------------------
__global__ __launch_bounds__(256) void gemm_mfma(
    const __hip_bfloat16* __restrict__ A,
    const __hip_bfloat16* __restrict__ Bt0, float* __restrict__ C0,
    const __hip_bfloat16* __restrict__ Bt1, float* __restrict__ C1,
    int Nb, int K, int ntiles_n)
{
    __shared__ __hip_bfloat16 As[128 * 32];
    __shared__ __hip_bfloat16 Bs[128 * 32];

    int t = threadIdx.x;
    int l = t & 63;
    int w = t >> 6;
    int wr = w >> 1, wc = w & 1;

    int bnt = blockIdx.x;
    const __hip_bfloat16* Bt = Bt0;
    float* C = C0;
    if (bnt >= ntiles_n) { Bt = Bt1; C = C1; bnt -= ntiles_n; }
    int bm = blockIdx.y * 128;
    int bn = bnt * 128;

    int srow = t >> 2;
    int skc  = (t & 3) * 8;
    const __hip_bfloat16* ga0 = A + (size_t)(bm + srow) * K + skc;
    const __hip_bfloat16* ga1 = A + (size_t)(bm + 64 + srow) * K + skc;
    const __hip_bfloat16* gb0 = Bt + (size_t)(bn + srow) * K + skc;
    const __hip_bfloat16* gb1 = Bt + (size_t)(bn + 64 + srow) * K + skc;
    __hip_bfloat16* lA0 = &As[(t & ~63) * 8];
    __hip_bfloat16* lA1 = &As[2048 + (t & ~63) * 8];
    __hip_bfloat16* lB0 = &Bs[(t & ~63) * 8];
    __hip_bfloat16* lB1 = &Bs[2048 + (t & ~63) * 8];

    f32x4 acc[4][4] = {};

    int aro = (wr * 64 + (l & 15)) * 32 + (l >> 4) * 8;
    int bro = (wc * 64 + (l & 15)) * 32 + (l >> 4) * 8;

    for (int k0 = 0; k0 < K; k0 += 32) {
        GLOAD_LDS16(ga0 + k0, lA0);
        GLOAD_LDS16(ga1 + k0, lA1);
        GLOAD_LDS16(gb0 + k0, lB0);
        GLOAD_LDS16(gb1 + k0, lB1);
        __syncthreads();

        short8 af[4], bf[4];
        #pragma unroll
        for (int m = 0; m < 4; ++m) af[m] = *(const short8*)&As[aro + m * 16 * 32];
        #pragma unroll
        for (int n = 0; n < 4; ++n) bf[n] = *(const short8*)&Bs[bro + n * 16 * 32];

        #pragma unroll
        for (int m = 0; m < 4; ++m)
            #pragma unroll
            for (int n = 0; n < 4; ++n)
                acc[m][n] = __builtin_amdgcn_mfma_f32_16x16x32_bf16(
                                af[m], bf[n], acc[m][n], 0, 0, 0);
        __syncthreads();
    }

    int crow = bm + wr * 64 + (l >> 4) * 4;
    int ccol = bn + wc * 64 + (l & 15);
    #pragma unroll
    for (int m = 0; m < 4; ++m)
        #pragma unroll
        for (int n = 0; n < 4; ++n)
            #pragma unroll
            for (int j = 0; j < 4; ++j)
                C[(size_t)(crow + m * 16 + j) * Nb + ccol + n * 16] = acc[m][n][j];
}

// ---------------------------------------------------------------------------
// Prep: one 64-thread wave per (h, n). Normalize q,k,v; gate = tanh(silu(g)).
// ---------------------------------------------------------------------------
__global__ __launch_bounds__(64) void prep_kernel(
    const float* __restrict__ qg, const float* __restrict__ kv,
    float* __restrict__ Q, float* __restrict__ Ko,
    float* __restrict__ V, float* __restrict__ G)
{
    int bid = blockIdx.x;
    int h = bid >> 12;
    int n = bid & (N_TOK - 1);
    int lane = threadIdx.x;

    const float* qgrow = qg + (size_t)n * QGN + h * QGW;
    const float* kvrow = kv + (size_t)n * QGN + h * QGW;

    float v = kvrow[DKQ + lane];
    float g = qgrow[DKQ + lane];
    float s = v * v;
    #pragma unroll
    for (int off = 32; off; off >>= 1) s += __shfl_xor(s, off);
    float vn = v / fmaxf(sqrtf(s), 1e-12f);
    V[((size_t)h * N_TOK + n) * DVH + lane] = vn;
    float sg = g / (1.f + expf(-g));
    G[((size_t)h * N_TOK + n) * DVH + lane] = tanhf(sg);

    if (lane < DKQ) {
        float q = qgrow[lane];
        float k = kvrow[lane];
        float sq = q * q, sk = k * k;
        #pragma unroll
        for (int off = 8; off; off >>= 1) {
            sq += __shfl_xor(sq, off);
            sk += __shfl_xor(sk, off);
        }
        Q [((size_t)h * N_TOK + n) * DKQ + lane] = q / fmaxf(sqrtf(sq), 1e-12f);
        Ko[((size_t)h * N_TOK + n) * DKQ + lane] = k / fmaxf(sqrtf(sk), 1e-12f);
    }
}

// ---------------------------------------------------------------------------
// Tiled banded attention + epilogue. Block = (h, 32 rows of i), 256 threads.
// j-band chunked by 64, K/V staged in LDS, soft window table per-d.
// ---------------------------------------------------------------------------
__global__ __launch_bounds__(256) void attn_tile_kernel(
    const float* __restrict__ Q, const float* __restrict__ Ko,
    const float* __restrict__ V, const float* __restrict__ G,
    const float* __restrict__ log_window, const float* __restrict__ log_r,
    const float* __restrict__ log_hscale, __hip_bfloat16* __restrict__ Y)
{
    int h  = blockIdx.x >> 7;            // 128 tiles per head
    int i0 = (blockIdx.x & 127) * TI;
    int t  = threadIdx.x;

    __shared__ float Q_lds[TI][16];
    __shared__ float K_lds[DC][16];
    __shared__ float V_lds[DC][DVH];
    __shared__ float att_lds[TI][68];
    __shared__ float soft_lds[260];

    float w  = expf(log_window[h]) + 1.f;
    float r  = expf(log_r[h]) + 1.f;
    float hs = expf(log_hscale[h]);
    int dmax = (int)ceilf(w) - 1;        // d in [0, dmax], dmax <= 256

    const float PI = 3.14159265358979f;
    for (int d = t; d <= dmax; d += 256)
        soft_lds[d] = 0.5f * (cosf(PI * (float)d / w) + 1.f);

    if (t < TI * 4) {
        int i = t >> 2, c = (t & 3) * 4;
        *(float4*)&Q_lds[i][c] =
            *(const float4*)(Q + ((size_t)h * N_TOK + i0 + i) * DKQ + c);
    }
    __syncthreads();

    // score mapping: i = i0 + (t&31), this thread scores 8 j's (jgrp)
    int i_loc = t & 31;
    int jgrp  = t >> 5;
    int i_glob = i0 + i_loc;
    float q[16];
    #pragma unroll
    for (int c = 0; c < 16; ++c) q[c] = Q_lds[i_loc][c];

    // PV mapping: wave wv, half ihalf -> 4 i's; lane pair dvp -> dv {2dvp, 2dvp+1}
    int wv = t >> 6, ihalf = (t >> 5) & 1, dvp = t & 31;
    int ib = wv * 8 + ihalf * 4;
    float acc[4][2] = {};

    int jstart = i0 - dmax; if (jstart < 0) jstart = 0;
    int span = i0 + TI - jstart;
    int nch = (span + DC - 1) / DC;

    for (int ch = 0; ch < nch; ++ch) {
        int j0 = jstart + ch * DC;
        __syncthreads();   // protect LDS from previous chunk's readers

        // stage K chunk (64 rows x 16)
        {
            int j = j0 + (t >> 2);
            int c = (t & 3) * 4;
            float4 kv = make_float4(0.f, 0.f, 0.f, 0.f);
            if (j < N_TOK)
                kv = *(const float4*)(Ko + ((size_t)h * N_TOK + j) * DKQ + c);
            *(float4*)&K_lds[t >> 2][c] = kv;
        }
        // stage V chunk (64 rows x 64)
        #pragma unroll
        for (int kk = 0; kk < 4; ++kk) {
            int f = t + kk * 256;
            int jc = f >> 4, c = (f & 15) * 4;
            int j = j0 + jc;
            float4 vv = make_float4(0.f, 0.f, 0.f, 0.f);
            if (j < N_TOK)
                vv = *(const float4*)(V + ((size_t)h * N_TOK + j) * DVH + c);
            *(float4*)&V_lds[jc][c] = vv;
        }
        __syncthreads();

        // scores -> att_lds
        #pragma unroll
        for (int jj = 0; jj < 8; ++jj) {
            int jc = jgrp * 8 + jj;
            int j = j0 + jc;
            int d = i_glob - j;
            float sim = 0.f;
            #pragma unroll
            for (int c4 = 0; c4 < 4; ++c4) {
                float4 kk4 = *(const float4*)&K_lds[jc][c4 * 4];
                sim += q[c4*4+0]*kk4.x + q[c4*4+1]*kk4.y
                     + q[c4*4+2]*kk4.z + q[c4*4+3]*kk4.w;
            }
            float a = fmaxf(1.f - r * (1.f - sim), 0.f);
            int dc = min(max(d, 0), dmax);           // clamp for safe LDS index
            bool valid = (d >= 0) && (d <= dmax);
            float av = valid ? a * a * soft_lds[dc] : 0.f;
            att_lds[i_loc][jc] = av;
        }
        __syncthreads();

        // PV: acc[m][0..1] over this chunk
        #pragma unroll
        for (int g4 = 0; g4 < 16; ++g4) {
            int jc0 = g4 * 4;
            float4 am[4];
            #pragma unroll
            for (int m = 0; m < 4; ++m)
                am[m] = *(const float4*)&att_lds[ib + m][jc0];
            float2 v0 = *(const float2*)&V_lds[jc0 + 0][dvp * 2];
            float2 v1 = *(const float2*)&V_lds[jc0 + 1][dvp * 2];
            float2 v2 = *(const float2*)&V_lds[jc0 + 2][dvp * 2];
            float2 v3 = *(const float2*)&V_lds[jc0 + 3][dvp * 2];
            #pragma unroll
            for (int m = 0; m < 4; ++m) {
                acc[m][0] += am[m].x * v0.x + am[m].y * v1.x
                           + am[m].z * v2.x + am[m].w * v3.x;
                acc[m][1] += am[m].x * v0.y + am[m].y * v1.y
                           + am[m].z * v2.y + am[m].w * v3.y;
            }
        }
    }

    // epilogue: per-i norm over dv (32 lanes per half-wave own all 64 dv)
    #pragma unroll
    for (int m = 0; m < 4; ++m) {
        float s = acc[m][0] * acc[m][0] + acc[m][1] * acc[m][1];
        #pragma unroll
        for (int off = 16; off; off >>= 1) s += __shfl_xor(s, off);
        float norm = sqrtf(s);
        float scale = tanhf(norm) / fmaxf(norm, 1e-12f);
        int i = i0 + ib + m;
        float2 g2 = *(const float2*)(G + ((size_t)h * N_TOK + i) * DVH + dvp * 2);
        float o0 = acc[m][0] * scale * g2.x * hs;
        float o1 = acc[m][1] * scale * g2.y * hs;
        __hip_bfloat16 ob[2] = { __float2bfloat16(o0), __float2bfloat16(o1) };
        *(ushort2*)(Y + (size_t)i * HD + h * DVH + dvp * 2) = *(const ushort2*)ob;
    }
}

// ---------------------------------------------------------------------------
extern "C" void kernel_launch(void* const* d_in, const int* in_sizes, int n_in,
                              void* d_out, int out_size, void* d_ws, size_t ws_size,
                              hipStream_t stream)
{
    const float* tokens     = (const float*)d_in[0];
    const float* w_qg       = (const float*)d_in[1];
    const float* w_kv       = (const float*)d_in[2];
    const float* w_out      = (const float*)d_in[3];
    const float* log_window = (const float*)d_in[4];
    const float* log_r      = (const float*)d_in[5];
    const float* log_hscale = (const float*)d_in[6];
    float* out = (float*)d_out;

    char* ws = (char*)d_ws;
    float* qg = (float*)ws;            ws += (size_t)N_TOK * QGN * 4;
    float* kv = (float*)ws;            ws += (size_t)N_TOK * QGN * 4;
    float* Q  = (float*)ws;            ws += (size_t)NHEAD * N_TOK * DKQ * 4;
    float* Ko = (float*)ws;            ws += (size_t)NHEAD * N_TOK * DKQ * 4;
    float* V  = (float*)ws;            ws += (size_t)NHEAD * N_TOK * DVH * 4;
    float* G  = (float*)ws;            ws += (size_t)NHEAD * N_TOK * DVH * 4;
    __hip_bfloat16* tokB  = (__hip_bfloat16*)ws; ws += (size_t)N_TOK * D_MODEL * 2;
    __hip_bfloat16* wqgT  = (__hip_bfloat16*)ws; ws += (size_t)QGN * D_MODEL * 2;
    __hip_bfloat16* wkvT  = (__hip_bfloat16*)ws; ws += (size_t)QGN * D_MODEL * 2;
    __hip_bfloat16* woutT = (__hip_bfloat16*)ws; ws += (size_t)D_MODEL * HD * 2;
    __hip_bfloat16* Yb    = (__hip_bfloat16*)ws; ws += (size_t)N_TOK * HD * 2;

    cast_bf16_kernel<<<(N_TOK * D_MODEL / 4 + 255) / 256, 256, 0, stream>>>(
        tokens, tokB, N_TOK * D_MODEL);
    {
        dim3 blk(32, 8);
        transpose_cast_kernel<<<dim3(QGN / 32, D_MODEL / 32), blk, 0, stream>>>(
            w_qg, wqgT, D_MODEL, QGN);
        transpose_cast_kernel<<<dim3(QGN / 32, D_MODEL / 32), blk, 0, stream>>>(
            w_kv, wkvT, D_MODEL, QGN);
        transpose_cast_kernel<<<dim3(D_MODEL / 32, HD / 32), blk, 0, stream>>>(
            w_out, woutT, HD, D_MODEL);
    }

    {
        dim3 grid(2 * (QGN / 128), N_TOK / 128);
        gemm_mfma<<<grid, 256, 0, stream>>>(tokB, wqgT, qg, wkvT, kv,
                                            QGN, D_MODEL, QGN / 128);
    }
    prep_kernel<<<NHEAD * N_TOK, 64, 0, stream>>>(qg, kv, Q, Ko, V, G);
    attn_tile_kernel<<<NHEAD * (N_TOK / TI), 256, 0, stream>>>(
        Q, Ko, V, G, log_window, log_r, log_hscale, Yb);
    {
        dim3 grid(D_MODEL / 128, N_TOK / 128);
        gemm_mfma<<<grid, 256, 0, stream>>>(Yb, woutT, out, woutT, out,
                                            D_MODEL, HD, D_MODEL / 128);
    }
}

// Round 5
// 113.230 us; speedup vs baseline: 2.7367x; 1.0435x over previous
//
#include <hip/hip_runtime.h>
#include <hip/hip_bf16.h>
#include <math.h>

#define N_TOK 4096
#define D_MODEL 1024
#define NHEAD 8
#define DKQ 16
#define DVH 64
#define QGW 80   // DK+DV columns per head
#define QGN 640  // H * 80
#define HD  512  // H * DV
#define TI  32   // attention: i-rows per block
#define DC  64   // attention: j-chunk width
#define NCH_MAX 5

typedef __attribute__((ext_vector_type(8))) short short8;
typedef __attribute__((ext_vector_type(4))) float f32x4;

#define GLOAD_LDS16(gp, lp) \
  __builtin_amdgcn_global_load_lds((const __attribute__((address_space(1))) void*)(gp), \
                                   (__attribute__((address_space(3))) void*)(lp), 16, 0, 0)

// ---------------------------------------------------------------------------
// fp32 -> bf16 elementwise cast (4 elems/thread)
// ---------------------------------------------------------------------------
__global__ __launch_bounds__(256) void cast_bf16_kernel(
    const float* __restrict__ in, __hip_bfloat16* __restrict__ out, int n)
{
    int i = (blockIdx.x * 256 + threadIdx.x) * 4;
    if (i >= n) return;
    float4 v = *(const float4*)(in + i);
    __hip_bfloat16 o[4] = { __float2bfloat16(v.x), __float2bfloat16(v.y),
                            __float2bfloat16(v.z), __float2bfloat16(v.w) };
    *(ushort4*)(out + i) = *(const ushort4*)o;
}

// ---------------------------------------------------------------------------
// transpose + cast: in fp32 [R][C] -> out bf16 [C][R]
// ---------------------------------------------------------------------------
__global__ __launch_bounds__(256) void transpose_cast_kernel(
    const float* __restrict__ in, __hip_bfloat16* __restrict__ out, int R, int C)
{
    __shared__ float tile[32][33];
    int bx = blockIdx.x * 32;
    int by = blockIdx.y * 32;
    int x = bx + threadIdx.x;
    for (int j = threadIdx.y; j < 32; j += 8) {
        int y = by + j;
        if (y < R && x < C) tile[j][threadIdx.x] = in[(size_t)y * C + x];
    }
    __syncthreads();
    int xo = by + threadIdx.x;
    for (int j = threadIdx.y; j < 32; j += 8) {
        int yo = bx + j;
        if (yo < C && xo < R)
            out[(size_t)yo * R + xo] = __float2bfloat16(tile[threadIdx.x][j]);
    }
}

// ---------------------------------------------------------------------------
// bf16 MFMA GEMM (m97 structure): C(fp32 MxNb) = A(bf16 MxK) * Bt(bf16 NbxK)^T
// ---------------------------------------------------------------------------
__global__ __launch_bounds__(256) void gemm_mfma(
    const __hip_bfloat16* __restrict__ A,
    const __hip_bfloat16* __restrict__ Bt0, float* __restrict__ C0,
    const __hip_bfloat16* __restrict__ Bt1, float* __restrict__ C1,
    int Nb, int K, int ntiles_n)
{
    __shared__ __hip_bfloat16 As[128 * 32];
    __shared__ __hip_bfloat16 Bs[128 * 32];

    int t = threadIdx.x;
    int l = t & 63;
    int w = t >> 6;
    int wr = w >> 1, wc = w & 1;

    int bnt = blockIdx.x;
    const __hip_bfloat16* Bt = Bt0;
    float* C = C0;
    if (bnt >= ntiles_n) { Bt = Bt1; C = C1; bnt -= ntiles_n; }
    int bm = blockIdx.y * 128;
    int bn = bnt * 128;

    int srow = t >> 2;
    int skc  = (t & 3) * 8;
    const __hip_bfloat16* ga0 = A + (size_t)(bm + srow) * K + skc;
    const __hip_bfloat16* ga1 = A + (size_t)(bm + 64 + srow) * K + skc;
    const __hip_bfloat16* gb0 = Bt + (size_t)(bn + srow) * K + skc;
    const __hip_bfloat16* gb1 = Bt + (size_t)(bn + 64 + srow) * K + skc;
    __hip_bfloat16* lA0 = &As[(t & ~63) * 8];
    __hip_bfloat16* lA1 = &As[2048 + (t & ~63) * 8];
    __hip_bfloat16* lB0 = &Bs[(t & ~63) * 8];
    __hip_bfloat16* lB1 = &Bs[2048 + (t & ~63) * 8];

    f32x4 acc[4][4] = {};

    int aro = (wr * 64 + (l & 15)) * 32 + (l >> 4) * 8;
    int bro = (wc * 64 + (l & 15)) * 32 + (l >> 4) * 8;

    for (int k0 = 0; k0 < K; k0 += 32) {
        GLOAD_LDS16(ga0 + k0, lA0);
        GLOAD_LDS16(ga1 + k0, lA1);
        GLOAD_LDS16(gb0 + k0, lB0);
        GLOAD_LDS16(gb1 + k0, lB1);
        __syncthreads();

        short8 af[4], bf[4];
        #pragma unroll
        for (int m = 0; m < 4; ++m) af[m] = *(const short8*)&As[aro + m * 16 * 32];
        #pragma unroll
        for (int n = 0; n < 4; ++n) bf[n] = *(const short8*)&Bs[bro + n * 16 * 32];

        #pragma unroll
        for (int m = 0; m < 4; ++m)
            #pragma unroll
            for (int n = 0; n < 4; ++n)
                acc[m][n] = __builtin_amdgcn_mfma_f32_16x16x32_bf16(
                                af[m], bf[n], acc[m][n], 0, 0, 0);
        __syncthreads();
    }

    int crow = bm + wr * 64 + (l >> 4) * 4;
    int ccol = bn + wc * 64 + (l & 15);
    #pragma unroll
    for (int m = 0; m < 4; ++m)
        #pragma unroll
        for (int n = 0; n < 4; ++n)
            #pragma unroll
            for (int j = 0; j < 4; ++j)
                C[(size_t)(crow + m * 16 + j) * Nb + ccol + n * 16] = acc[m][n][j];
}

// ---------------------------------------------------------------------------
// Prep: one 64-thread wave per (h, n). Normalize q,k,v; gate = tanh(silu(g)).
// ---------------------------------------------------------------------------
__global__ __launch_bounds__(64) void prep_kernel(
    const float* __restrict__ qg, const float* __restrict__ kv,
    float* __restrict__ Q, float* __restrict__ Ko,
    float* __restrict__ V, float* __restrict__ G)
{
    int bid = blockIdx.x;
    int h = bid >> 12;
    int n = bid & (N_TOK - 1);
    int lane = threadIdx.x;

    const float* qgrow = qg + (size_t)n * QGN + h * QGW;
    const float* kvrow = kv + (size_t)n * QGN + h * QGW;

    float v = kvrow[DKQ + lane];
    float g = qgrow[DKQ + lane];
    float s = v * v;
    #pragma unroll
    for (int off = 32; off; off >>= 1) s += __shfl_xor(s, off);
    float vn = v / fmaxf(sqrtf(s), 1e-12f);
    V[((size_t)h * N_TOK + n) * DVH + lane] = vn;
    float sg = g / (1.f + expf(-g));
    G[((size_t)h * N_TOK + n) * DVH + lane] = tanhf(sg);

    if (lane < DKQ) {
        float q = qgrow[lane];
        float k = kvrow[lane];
        float sq = q * q, sk = k * k;
        #pragma unroll
        for (int off = 8; off; off >>= 1) {
            sq += __shfl_xor(sq, off);
            sk += __shfl_xor(sk, off);
        }
        Q [((size_t)h * N_TOK + n) * DKQ + lane] = q / fmaxf(sqrtf(sq), 1e-12f);
        Ko[((size_t)h * N_TOK + n) * DKQ + lane] = k / fmaxf(sqrtf(sk), 1e-12f);
    }
}

// ---------------------------------------------------------------------------
// Chunk-parallel banded attention. Block = (h, i-tile of 32, chunk-slot).
// Each block computes the partial PV of ONE 64-wide j-chunk and stores it to
// Ypart[slot][i][h*64+dv]. No serial chunk loop, no atomics.
// ---------------------------------------------------------------------------
__global__ __launch_bounds__(256) void attn_chunk_kernel(
    const float* __restrict__ Q, const float* __restrict__ Ko,
    const float* __restrict__ V,
    const float* __restrict__ log_window, const float* __restrict__ log_r,
    float* __restrict__ Ypart)
{
    int bid = blockIdx.x;                 // h*(128*NCH_MAX) + tile*NCH_MAX + slot
    int h    = bid / (128 * NCH_MAX);
    int rem  = bid - h * (128 * NCH_MAX);
    int tile = rem / NCH_MAX;
    int slot = rem - tile * NCH_MAX;
    int i0 = tile * TI;
    int t = threadIdx.x;

    float w = expf(log_window[h]) + 1.f;
    float r = expf(log_r[h]) + 1.f;
    int dmax = (int)ceilf(w) - 1;         // <= 256
    int jstart = i0 - dmax; if (jstart < 0) jstart = 0;
    int span = i0 + TI - jstart;
    int nch = (span + DC - 1) / DC;
    if (slot >= nch) return;              // uniform exit, no syncs crossed
    int j0 = jstart + slot * DC;

    __shared__ float Q_lds[TI][16];
    __shared__ float K_lds[DC][16];
    __shared__ float V_lds[DC][DVH];
    __shared__ float att_lds[TI][68];
    __shared__ float soft_lds[288];

    const float PI = 3.14159265358979f;
    for (int d = t; d <= dmax; d += 256)
        soft_lds[d] = 0.5f * (cosf(PI * (float)d / w) + 1.f);

    if (t < TI * 4) {
        int i = t >> 2, c = (t & 3) * 4;
        *(float4*)&Q_lds[i][c] =
            *(const float4*)(Q + ((size_t)h * N_TOK + i0 + i) * DKQ + c);
    }
    // stage K chunk (64 x 16)
    {
        int j = j0 + (t >> 2);
        int c = (t & 3) * 4;
        float4 kvv = make_float4(0.f, 0.f, 0.f, 0.f);
        if (j < N_TOK)
            kvv = *(const float4*)(Ko + ((size_t)h * N_TOK + j) * DKQ + c);
        *(float4*)&K_lds[t >> 2][c] = kvv;
    }
    // stage V chunk (64 x 64)
    #pragma unroll
    for (int kk = 0; kk < 4; ++kk) {
        int f = t + kk * 256;
        int jc = f >> 4, c = (f & 15) * 4;
        int j = j0 + jc;
        float4 vv = make_float4(0.f, 0.f, 0.f, 0.f);
        if (j < N_TOK)
            vv = *(const float4*)(V + ((size_t)h * N_TOK + j) * DVH + c);
        *(float4*)&V_lds[jc][c] = vv;
    }
    __syncthreads();

    // scores: i = i0 + (t&31); this thread scores 8 j's
    int i_loc = t & 31;
    int jgrp  = t >> 5;
    int i_glob = i0 + i_loc;
    float q[16];
    #pragma unroll
    for (int c = 0; c < 16; ++c) q[c] = Q_lds[i_loc][c];

    #pragma unroll
    for (int jj = 0; jj < 8; ++jj) {
        int jc = jgrp * 8 + jj;
        int j = j0 + jc;
        int d = i_glob - j;
        float sim = 0.f;
        #pragma unroll
        for (int c4 = 0; c4 < 4; ++c4) {
            float4 kk4 = *(const float4*)&K_lds[jc][c4 * 4];
            sim += q[c4*4+0]*kk4.x + q[c4*4+1]*kk4.y
                 + q[c4*4+2]*kk4.z + q[c4*4+3]*kk4.w;
        }
        float a = fmaxf(1.f - r * (1.f - sim), 0.f);
        int dc = min(max(d, 0), dmax);
        bool valid = (d >= 0) && (d <= dmax);
        att_lds[i_loc][jc] = valid ? a * a * soft_lds[dc] : 0.f;
    }
    __syncthreads();

    // PV: wave wv, half ihalf -> 4 i's; lane pair dvp -> dv {2dvp, 2dvp+1}
    int wv = t >> 6, ihalf = (t >> 5) & 1, dvp = t & 31;
    int ib = wv * 8 + ihalf * 4;
    float acc[4][2] = {};

    #pragma unroll
    for (int g4 = 0; g4 < 16; ++g4) {
        int jc0 = g4 * 4;
        float4 am[4];
        #pragma unroll
        for (int m = 0; m < 4; ++m)
            am[m] = *(const float4*)&att_lds[ib + m][jc0];
        float2 v0 = *(const float2*)&V_lds[jc0 + 0][dvp * 2];
        float2 v1 = *(const float2*)&V_lds[jc0 + 1][dvp * 2];
        float2 v2 = *(const float2*)&V_lds[jc0 + 2][dvp * 2];
        float2 v3 = *(const float2*)&V_lds[jc0 + 3][dvp * 2];
        #pragma unroll
        for (int m = 0; m < 4; ++m) {
            acc[m][0] += am[m].x * v0.x + am[m].y * v1.x
                       + am[m].z * v2.x + am[m].w * v3.x;
            acc[m][1] += am[m].x * v0.y + am[m].y * v1.y
                       + am[m].z * v2.y + am[m].w * v3.y;
        }
    }

    // store partial: Ypart[slot][i][h*64+dv]
    #pragma unroll
    for (int m = 0; m < 4; ++m) {
        int i = i0 + ib + m;
        float2 st = make_float2(acc[m][0], acc[m][1]);
        *(float2*)(Ypart + ((size_t)slot * N_TOK + i) * HD + h * DVH + dvp * 2) = st;
    }
}

// ---------------------------------------------------------------------------
// Epilogue: sum chunk partials, norm/tanh/gate/hscale, write bf16 Y.
// One wave per (h, i); 4 waves per block.
// ---------------------------------------------------------------------------
__global__ __launch_bounds__(256) void attn_epilogue_kernel(
    const float* __restrict__ Ypart, const float* __restrict__ G,
    const float* __restrict__ log_window, const float* __restrict__ log_hscale,
    __hip_bfloat16* __restrict__ Y)
{
    int wv = threadIdx.x >> 6, lane = threadIdx.x & 63;
    int gid = blockIdx.x * 4 + wv;        // h*N_TOK + i
    int h = gid >> 12;
    int i = gid & (N_TOK - 1);

    float w  = expf(log_window[h]) + 1.f;
    float hs = expf(log_hscale[h]);
    int dmax = (int)ceilf(w) - 1;
    int i0 = i & ~(TI - 1);
    int jstart = i0 - dmax; if (jstart < 0) jstart = 0;
    int nch = (i0 + TI - jstart + DC - 1) / DC;

    size_t base = (size_t)i * HD + h * DVH + lane;
    float a = 0.f;
    for (int c = 0; c < nch; ++c)
        a += Ypart[(size_t)c * N_TOK * HD + base];

    float ss = a * a;
    #pragma unroll
    for (int off = 32; off; off >>= 1) ss += __shfl_xor(ss, off);
    float norm = sqrtf(ss);
    float scale = tanhf(norm) / fmaxf(norm, 1e-12f);

    float o = a * scale * G[((size_t)h * N_TOK + i) * DVH + lane] * hs;
    Y[(size_t)i * HD + h * DVH + lane] = __float2bfloat16(o);
}

// ---------------------------------------------------------------------------
extern "C" void kernel_launch(void* const* d_in, const int* in_sizes, int n_in,
                              void* d_out, int out_size, void* d_ws, size_t ws_size,
                              hipStream_t stream)
{
    const float* tokens     = (const float*)d_in[0];
    const float* w_qg       = (const float*)d_in[1];
    const float* w_kv       = (const float*)d_in[2];
    const float* w_out      = (const float*)d_in[3];
    const float* log_window = (const float*)d_in[4];
    const float* log_r      = (const float*)d_in[5];
    const float* log_hscale = (const float*)d_in[6];
    float* out = (float*)d_out;

    char* ws = (char*)d_ws;
    float* qg = (float*)ws;            ws += (size_t)N_TOK * QGN * 4;
    float* kv = (float*)ws;            ws += (size_t)N_TOK * QGN * 4;
    float* Q  = (float*)ws;            ws += (size_t)NHEAD * N_TOK * DKQ * 4;
    float* Ko = (float*)ws;            ws += (size_t)NHEAD * N_TOK * DKQ * 4;
    float* V  = (float*)ws;            ws += (size_t)NHEAD * N_TOK * DVH * 4;
    float* G  = (float*)ws;            ws += (size_t)NHEAD * N_TOK * DVH * 4;
    __hip_bfloat16* tokB  = (__hip_bfloat16*)ws; ws += (size_t)N_TOK * D_MODEL * 2;
    __hip_bfloat16* wqgT  = (__hip_bfloat16*)ws; ws += (size_t)QGN * D_MODEL * 2;
    __hip_bfloat16* wkvT  = (__hip_bfloat16*)ws; ws += (size_t)QGN * D_MODEL * 2;
    __hip_bfloat16* woutT = (__hip_bfloat16*)ws; ws += (size_t)D_MODEL * HD * 2;
    __hip_bfloat16* Yb    = (__hip_bfloat16*)ws; ws += (size_t)N_TOK * HD * 2;
    float* Ypart = (float*)ws;         ws += (size_t)NCH_MAX * N_TOK * HD * 4; // 40 MB

    cast_bf16_kernel<<<(N_TOK * D_MODEL / 4 + 255) / 256, 256, 0, stream>>>(
        tokens, tokB, N_TOK * D_MODEL);
    {
        dim3 blk(32, 8);
        transpose_cast_kernel<<<dim3(QGN / 32, D_MODEL / 32), blk, 0, stream>>>(
            w_qg, wqgT, D_MODEL, QGN);
        transpose_cast_kernel<<<dim3(QGN / 32, D_MODEL / 32), blk, 0, stream>>>(
            w_kv, wkvT, D_MODEL, QGN);
        transpose_cast_kernel<<<dim3(D_MODEL / 32, HD / 32), blk, 0, stream>>>(
            w_out, woutT, HD, D_MODEL);
    }

    {
        dim3 grid(2 * (QGN / 128), N_TOK / 128);
        gemm_mfma<<<grid, 256, 0, stream>>>(tokB, wqgT, qg, wkvT, kv,
                                            QGN, D_MODEL, QGN / 128);
    }
    prep_kernel<<<NHEAD * N_TOK, 64, 0, stream>>>(qg, kv, Q, Ko, V, G);
    attn_chunk_kernel<<<NHEAD * (N_TOK / TI) * NCH_MAX, 256, 0, stream>>>(
        Q, Ko, V, log_window, log_r, Ypart);
    attn_epilogue_kernel<<<NHEAD * N_TOK / 4, 256, 0, stream>>>(
        Ypart, G, log_window, log_hscale, Yb);
    {
        dim3 grid(D_MODEL / 128, N_TOK / 128);
        gemm_mfma<<<grid, 256, 0, stream>>>(Yb, woutT, out, woutT, out,
                                            D_MODEL, HD, D_MODEL / 128);
    }
}

// Round 6
// 98.331 us; speedup vs baseline: 3.1514x; 1.1515x over previous
//
#include <hip/hip_runtime.h>
#include <hip/hip_bf16.h>
#include <math.h>

#define N_TOK 4096
#define D_MODEL 1024
#define NHEAD 8
#define DKQ 16
#define DVH 64
#define QGW 80   // DK+DV columns per head
#define QGN 640  // H * 80
#define HD  512  // H * DV
#define TI  32   // attention: i-rows per tile
#define DC  64   // attention: j-chunk width
#define NCH_MAX 5

typedef __attribute__((ext_vector_type(8))) short short8;
typedef __attribute__((ext_vector_type(4))) float f32x4;

#define GLOAD_LDS16(gp, lp) \
  __builtin_amdgcn_global_load_lds((const __attribute__((address_space(1))) void*)(gp), \
                                   (__attribute__((address_space(3))) void*)(lp), 16, 0, 0)

// ---------------------------------------------------------------------------
// pack: tokens fp32->bf16 cast, plus 3 weight transpose+casts, by block range.
//   blocks [0,4096): tokens cast (1024 elems/block)
//   [4096,4736): w_qg  [1024][640] -> wqgT  [640][1024]
//   [4736,5376): w_kv  [1024][640] -> wkvT  [640][1024]
//   [5376,5888): w_out [512][1024] -> woutT [1024][512]
// ---------------------------------------------------------------------------
__global__ __launch_bounds__(256) void pack_kernel(
    const float* __restrict__ tokens, const float* __restrict__ w_qg,
    const float* __restrict__ w_kv, const float* __restrict__ w_out,
    __hip_bfloat16* __restrict__ tokB, __hip_bfloat16* __restrict__ wqgT,
    __hip_bfloat16* __restrict__ wkvT, __hip_bfloat16* __restrict__ woutT)
{
    __shared__ float tile[32][33];
    int b = blockIdx.x;
    int t = threadIdx.x;

    if (b < 4096) {                       // tokens cast
        int i = (b * 256 + t) * 4;
        float4 v = *(const float4*)(tokens + i);
        __hip_bfloat16 o[4] = { __float2bfloat16(v.x), __float2bfloat16(v.y),
                                __float2bfloat16(v.z), __float2bfloat16(v.w) };
        *(ushort4*)(tokB + i) = *(const ushort4*)o;
        return;
    }

    const float* in; __hip_bfloat16* outp; int R, C, tb;
    if (b < 4736)      { in = w_qg;  outp = wqgT;  R = 1024; C = 640;  tb = b - 4096; }
    else if (b < 5376) { in = w_kv;  outp = wkvT;  R = 1024; C = 640;  tb = b - 4736; }
    else               { in = w_out; outp = woutT; R = 512;  C = 1024; tb = b - 5376; }
    int ctiles = C / 32;
    int bx = (tb % ctiles) * 32;          // input col base
    int by = (tb / ctiles) * 32;          // input row base
    int tx = t & 31, ty = t >> 5;         // 32 x 8

    #pragma unroll
    for (int j = 0; j < 32; j += 8)
        tile[j + ty][tx] = in[(size_t)(by + j + ty) * C + bx + tx];
    __syncthreads();
    #pragma unroll
    for (int j = 0; j < 32; j += 8)
        outp[(size_t)(bx + j + ty) * R + by + tx] =
            __float2bfloat16(tile[tx][j + ty]);
}

// ---------------------------------------------------------------------------
// bf16 MFMA GEMM (m97 structure): C(fp32 MxNb) = A(bf16 MxK) * Bt(bf16 NbxK)^T
// ---------------------------------------------------------------------------
__global__ __launch_bounds__(256) void gemm_mfma(
    const __hip_bfloat16* __restrict__ A,
    const __hip_bfloat16* __restrict__ Bt0, float* __restrict__ C0,
    const __hip_bfloat16* __restrict__ Bt1, float* __restrict__ C1,
    int Nb, int K, int ntiles_n)
{
    __shared__ __hip_bfloat16 As[128 * 32];
    __shared__ __hip_bfloat16 Bs[128 * 32];

    int t = threadIdx.x;
    int l = t & 63;
    int w = t >> 6;
    int wr = w >> 1, wc = w & 1;

    int bnt = blockIdx.x;
    const __hip_bfloat16* Bt = Bt0;
    float* C = C0;
    if (bnt >= ntiles_n) { Bt = Bt1; C = C1; bnt -= ntiles_n; }
    int bm = blockIdx.y * 128;
    int bn = bnt * 128;

    int srow = t >> 2;
    int skc  = (t & 3) * 8;
    const __hip_bfloat16* ga0 = A + (size_t)(bm + srow) * K + skc;
    const __hip_bfloat16* ga1 = A + (size_t)(bm + 64 + srow) * K + skc;
    const __hip_bfloat16* gb0 = Bt + (size_t)(bn + srow) * K + skc;
    const __hip_bfloat16* gb1 = Bt + (size_t)(bn + 64 + srow) * K + skc;
    __hip_bfloat16* lA0 = &As[(t & ~63) * 8];
    __hip_bfloat16* lA1 = &As[2048 + (t & ~63) * 8];
    __hip_bfloat16* lB0 = &Bs[(t & ~63) * 8];
    __hip_bfloat16* lB1 = &Bs[2048 + (t & ~63) * 8];

    f32x4 acc[4][4] = {};

    int aro = (wr * 64 + (l & 15)) * 32 + (l >> 4) * 8;
    int bro = (wc * 64 + (l & 15)) * 32 + (l >> 4) * 8;

    for (int k0 = 0; k0 < K; k0 += 32) {
        GLOAD_LDS16(ga0 + k0, lA0);
        GLOAD_LDS16(ga1 + k0, lA1);
        GLOAD_LDS16(gb0 + k0, lB0);
        GLOAD_LDS16(gb1 + k0, lB1);
        __syncthreads();

        short8 af[4], bf[4];
        #pragma unroll
        for (int m = 0; m < 4; ++m) af[m] = *(const short8*)&As[aro + m * 16 * 32];
        #pragma unroll
        for (int n = 0; n < 4; ++n) bf[n] = *(const short8*)&Bs[bro + n * 16 * 32];

        #pragma unroll
        for (int m = 0; m < 4; ++m)
            #pragma unroll
            for (int n = 0; n < 4; ++n)
                acc[m][n] = __builtin_amdgcn_mfma_f32_16x16x32_bf16(
                                af[m], bf[n], acc[m][n], 0, 0, 0);
        __syncthreads();
    }

    int crow = bm + wr * 64 + (l >> 4) * 4;
    int ccol = bn + wc * 64 + (l & 15);
    #pragma unroll
    for (int m = 0; m < 4; ++m)
        #pragma unroll
        for (int n = 0; n < 4; ++n)
            #pragma unroll
            for (int j = 0; j < 4; ++j)
                C[(size_t)(crow + m * 16 + j) * Nb + ccol + n * 16] = acc[m][n][j];
}

// ---------------------------------------------------------------------------
// Chunk-parallel banded attention with fused normalization.
// Block = (h, i-tile of 32, chunk-slot). Reads raw qg/kv; normalizes q,k,v
// during LDS staging via lane-group shuffle reduction. Partial PV -> Ypart.
// ---------------------------------------------------------------------------
__global__ __launch_bounds__(256) void attn_chunk_kernel(
    const float* __restrict__ qg, const float* __restrict__ kv,
    const float* __restrict__ log_window, const float* __restrict__ log_r,
    float* __restrict__ Ypart)
{
    int bid = blockIdx.x;                 // h*(128*NCH_MAX) + tile*NCH_MAX + slot
    int h    = bid / (128 * NCH_MAX);
    int rem  = bid - h * (128 * NCH_MAX);
    int tile = rem / NCH_MAX;
    int slot = rem - tile * NCH_MAX;
    int i0 = tile * TI;
    int t = threadIdx.x;

    float w = expf(log_window[h]) + 1.f;
    float r = expf(log_r[h]) + 1.f;
    int dmax = (int)ceilf(w) - 1;         // <= 256
    int jstart = i0 - dmax; if (jstart < 0) jstart = 0;
    int nch = (i0 + TI - jstart + DC - 1) / DC;
    if (slot >= nch) return;              // uniform block exit
    int j0 = jstart + slot * DC;

    __shared__ float Q_lds[TI][16];
    __shared__ float K_lds[DC][16];
    __shared__ float V_lds[DC][DVH];
    __shared__ float att_lds[TI][68];
    __shared__ float soft_lds[288];

    const float PI = 3.14159265358979f;
    for (int d = t; d <= dmax; d += 256)
        soft_lds[d] = 0.5f * (cosf(PI * (float)d / w) + 1.f);

    // Q stage + normalize (rows i0..i0+31, 4 lanes/row)
    if (t < TI * 4) {
        int iq = t >> 2, c = (t & 3) * 4;
        float4 qv = *(const float4*)(qg + (size_t)(i0 + iq) * QGN + h * QGW + c);
        float s = qv.x*qv.x + qv.y*qv.y + qv.z*qv.z + qv.w*qv.w;
        s += __shfl_xor(s, 1); s += __shfl_xor(s, 2);
        float inv = 1.f / fmaxf(sqrtf(s), 1e-12f);
        qv.x *= inv; qv.y *= inv; qv.z *= inv; qv.w *= inv;
        *(float4*)&Q_lds[iq][c] = qv;
    }
    // K stage + normalize (64 rows, 4 lanes/row)
    {
        int jr = t >> 2, c = (t & 3) * 4;
        int j = j0 + jr;
        float4 kx = make_float4(0.f, 0.f, 0.f, 0.f);
        if (j < N_TOK)
            kx = *(const float4*)(kv + (size_t)j * QGN + h * QGW + c);
        float s = kx.x*kx.x + kx.y*kx.y + kx.z*kx.z + kx.w*kx.w;
        s += __shfl_xor(s, 1); s += __shfl_xor(s, 2);
        float inv = 1.f / fmaxf(sqrtf(s), 1e-12f);
        kx.x *= inv; kx.y *= inv; kx.z *= inv; kx.w *= inv;
        *(float4*)&K_lds[jr][c] = kx;
    }
    // V stage + normalize (64 rows x 64, 16 lanes/row)
    #pragma unroll
    for (int kk = 0; kk < 4; ++kk) {
        int f = t + kk * 256;
        int jc = f >> 4, c = (f & 15) * 4;
        int j = j0 + jc;
        float4 vx = make_float4(0.f, 0.f, 0.f, 0.f);
        if (j < N_TOK)
            vx = *(const float4*)(kv + (size_t)j * QGN + h * QGW + DKQ + c);
        float s = vx.x*vx.x + vx.y*vx.y + vx.z*vx.z + vx.w*vx.w;
        s += __shfl_xor(s, 1); s += __shfl_xor(s, 2);
        s += __shfl_xor(s, 4); s += __shfl_xor(s, 8);
        float inv = 1.f / fmaxf(sqrtf(s), 1e-12f);
        vx.x *= inv; vx.y *= inv; vx.z *= inv; vx.w *= inv;
        *(float4*)&V_lds[jc][c] = vx;
    }
    __syncthreads();

    // scores: i = i0 + (t&31); this thread scores 8 j's
    int i_loc = t & 31;
    int jgrp  = t >> 5;
    int i_glob = i0 + i_loc;
    float q[16];
    #pragma unroll
    for (int c = 0; c < 16; ++c) q[c] = Q_lds[i_loc][c];

    #pragma unroll
    for (int jj = 0; jj < 8; ++jj) {
        int jc = jgrp * 8 + jj;
        int j = j0 + jc;
        int d = i_glob - j;
        float sim = 0.f;
        #pragma unroll
        for (int c4 = 0; c4 < 4; ++c4) {
            float4 kk4 = *(const float4*)&K_lds[jc][c4 * 4];
            sim += q[c4*4+0]*kk4.x + q[c4*4+1]*kk4.y
                 + q[c4*4+2]*kk4.z + q[c4*4+3]*kk4.w;
        }
        float a = fmaxf(1.f - r * (1.f - sim), 0.f);
        int dc = min(max(d, 0), dmax);
        bool valid = (d >= 0) && (d <= dmax);
        att_lds[i_loc][jc] = valid ? a * a * soft_lds[dc] : 0.f;
    }
    __syncthreads();

    // PV: wave wv, half ihalf -> 4 i's; lane pair dvp -> dv {2dvp, 2dvp+1}
    int wv = t >> 6, ihalf = (t >> 5) & 1, dvp = t & 31;
    int ib = wv * 8 + ihalf * 4;
    float acc[4][2] = {};

    #pragma unroll
    for (int g4 = 0; g4 < 16; ++g4) {
        int jc0 = g4 * 4;
        float4 am[4];
        #pragma unroll
        for (int m = 0; m < 4; ++m)
            am[m] = *(const float4*)&att_lds[ib + m][jc0];
        float2 v0 = *(const float2*)&V_lds[jc0 + 0][dvp * 2];
        float2 v1 = *(const float2*)&V_lds[jc0 + 1][dvp * 2];
        float2 v2 = *(const float2*)&V_lds[jc0 + 2][dvp * 2];
        float2 v3 = *(const float2*)&V_lds[jc0 + 3][dvp * 2];
        #pragma unroll
        for (int m = 0; m < 4; ++m) {
            acc[m][0] += am[m].x * v0.x + am[m].y * v1.x
                       + am[m].z * v2.x + am[m].w * v3.x;
            acc[m][1] += am[m].x * v0.y + am[m].y * v1.y
                       + am[m].z * v2.y + am[m].w * v3.y;
        }
    }

    #pragma unroll
    for (int m = 0; m < 4; ++m) {
        int i = i0 + ib + m;
        float2 st = make_float2(acc[m][0], acc[m][1]);
        *(float2*)(Ypart + ((size_t)slot * N_TOK + i) * HD + h * DVH + dvp * 2) = st;
    }
}

// ---------------------------------------------------------------------------
// Epilogue: sum chunk partials, norm/tanh, gate from raw qg, hscale -> bf16 Y.
// One wave per (h, i); 4 waves per block.
// ---------------------------------------------------------------------------
__global__ __launch_bounds__(256) void attn_epilogue_kernel(
    const float* __restrict__ Ypart, const float* __restrict__ qg,
    const float* __restrict__ log_window, const float* __restrict__ log_hscale,
    __hip_bfloat16* __restrict__ Y)
{
    int wv = threadIdx.x >> 6, lane = threadIdx.x & 63;
    int gid = blockIdx.x * 4 + wv;        // h*N_TOK + i
    int h = gid >> 12;
    int i = gid & (N_TOK - 1);

    float w  = expf(log_window[h]) + 1.f;
    float hs = expf(log_hscale[h]);
    int dmax = (int)ceilf(w) - 1;
    int i0 = i & ~(TI - 1);
    int jstart = i0 - dmax; if (jstart < 0) jstart = 0;
    int nch = (i0 + TI - jstart + DC - 1) / DC;

    size_t base = (size_t)i * HD + h * DVH + lane;
    float a = 0.f;
    for (int c = 0; c < nch; ++c)
        a += Ypart[(size_t)c * N_TOK * HD + base];

    float g = qg[(size_t)i * QGN + h * QGW + DKQ + lane];
    float gate = tanhf(g / (1.f + expf(-g)));

    float ss = a * a;
    #pragma unroll
    for (int off = 32; off; off >>= 1) ss += __shfl_xor(ss, off);
    float norm = sqrtf(ss);
    float scale = tanhf(norm) / fmaxf(norm, 1e-12f);

    float o = a * scale * gate * hs;
    Y[(size_t)i * HD + h * DVH + lane] = __float2bfloat16(o);
}

// ---------------------------------------------------------------------------
extern "C" void kernel_launch(void* const* d_in, const int* in_sizes, int n_in,
                              void* d_out, int out_size, void* d_ws, size_t ws_size,
                              hipStream_t stream)
{
    const float* tokens     = (const float*)d_in[0];
    const float* w_qg       = (const float*)d_in[1];
    const float* w_kv       = (const float*)d_in[2];
    const float* w_out      = (const float*)d_in[3];
    const float* log_window = (const float*)d_in[4];
    const float* log_r      = (const float*)d_in[5];
    const float* log_hscale = (const float*)d_in[6];
    float* out = (float*)d_out;

    char* ws = (char*)d_ws;
    float* qg = (float*)ws;            ws += (size_t)N_TOK * QGN * 4;     // 10.5 MB
    float* kv = (float*)ws;            ws += (size_t)N_TOK * QGN * 4;     // 10.5 MB
    __hip_bfloat16* tokB  = (__hip_bfloat16*)ws; ws += (size_t)N_TOK * D_MODEL * 2;
    __hip_bfloat16* wqgT  = (__hip_bfloat16*)ws; ws += (size_t)QGN * D_MODEL * 2;
    __hip_bfloat16* wkvT  = (__hip_bfloat16*)ws; ws += (size_t)QGN * D_MODEL * 2;
    __hip_bfloat16* woutT = (__hip_bfloat16*)ws; ws += (size_t)D_MODEL * HD * 2;
    __hip_bfloat16* Yb    = (__hip_bfloat16*)ws; ws += (size_t)N_TOK * HD * 2;
    float* Ypart = (float*)ws;         ws += (size_t)NCH_MAX * N_TOK * HD * 4; // 40 MB

    // 0) pack: tokens cast + 3 weight transposes (one dispatch)
    pack_kernel<<<5888, 256, 0, stream>>>(tokens, w_qg, w_kv, w_out,
                                          tokB, wqgT, wkvT, woutT);
    // 1) qg = tokens @ w_qg, kv = tokens @ w_kv  (dual-B MFMA GEMM)
    {
        dim3 grid(2 * (QGN / 128), N_TOK / 128);
        gemm_mfma<<<grid, 256, 0, stream>>>(tokB, wqgT, qg, wkvT, kv,
                                            QGN, D_MODEL, QGN / 128);
    }
    // 2) chunk-parallel attention (fused normalization)
    attn_chunk_kernel<<<NHEAD * (N_TOK / TI) * NCH_MAX, 256, 0, stream>>>(
        qg, kv, log_window, log_r, Ypart);
    // 3) epilogue (fused gate)
    attn_epilogue_kernel<<<NHEAD * N_TOK / 4, 256, 0, stream>>>(
        Ypart, qg, log_window, log_hscale, Yb);
    // 4) out = Y @ w_out
    {
        dim3 grid(D_MODEL / 128, N_TOK / 128);
        gemm_mfma<<<grid, 256, 0, stream>>>(Yb, woutT, out, woutT, out,
                                            D_MODEL, HD, D_MODEL / 128);
    }
}

// Round 7
// 87.009 us; speedup vs baseline: 3.5615x; 1.1301x over previous
//
#include <hip/hip_runtime.h>
#include <hip/hip_bf16.h>
#include <math.h>

#define N_TOK 4096
#define D_MODEL 1024
#define NHEAD 8
#define DKQ 16
#define DVH 64
#define QGW 80   // DK+DV columns per head
#define QGN 640  // H * 80
#define HD  512  // H * DV
#define TI  32   // attention: i-rows per tile
#define DC  64   // attention: j-chunk width
#define NCH_MAX 5

typedef __attribute__((ext_vector_type(8))) short short8;
typedef __attribute__((ext_vector_type(4))) float f32x4;

#define GLOAD_LDS16(gp, lp) \
  __builtin_amdgcn_global_load_lds((const __attribute__((address_space(1))) void*)(gp), \
                                   (__attribute__((address_space(3))) void*)(lp), 16, 0, 0)

// ---------------------------------------------------------------------------
// pack: tokens fp32->bf16 cast, plus 3 weight transpose+casts, by block range.
// ---------------------------------------------------------------------------
__global__ __launch_bounds__(256) void pack_kernel(
    const float* __restrict__ tokens, const float* __restrict__ w_qg,
    const float* __restrict__ w_kv, const float* __restrict__ w_out,
    __hip_bfloat16* __restrict__ tokB, __hip_bfloat16* __restrict__ wqgT,
    __hip_bfloat16* __restrict__ wkvT, __hip_bfloat16* __restrict__ woutT)
{
    __shared__ float tile[32][33];
    int b = blockIdx.x;
    int t = threadIdx.x;

    if (b < 4096) {                       // tokens cast
        int i = (b * 256 + t) * 4;
        float4 v = *(const float4*)(tokens + i);
        __hip_bfloat16 o[4] = { __float2bfloat16(v.x), __float2bfloat16(v.y),
                                __float2bfloat16(v.z), __float2bfloat16(v.w) };
        *(ushort4*)(tokB + i) = *(const ushort4*)o;
        return;
    }

    const float* in; __hip_bfloat16* outp; int R, C, tb;
    if (b < 4736)      { in = w_qg;  outp = wqgT;  R = 1024; C = 640;  tb = b - 4096; }
    else if (b < 5376) { in = w_kv;  outp = wkvT;  R = 1024; C = 640;  tb = b - 4736; }
    else               { in = w_out; outp = woutT; R = 512;  C = 1024; tb = b - 5376; }
    int ctiles = C / 32;
    int bx = (tb % ctiles) * 32;
    int by = (tb / ctiles) * 32;
    int tx = t & 31, ty = t >> 5;

    #pragma unroll
    for (int j = 0; j < 32; j += 8)
        tile[j + ty][tx] = in[(size_t)(by + j + ty) * C + bx + tx];
    __syncthreads();
    #pragma unroll
    for (int j = 0; j < 32; j += 8)
        outp[(size_t)(bx + j + ty) * R + by + tx] =
            __float2bfloat16(tile[tx][j + ty]);
}

// ---------------------------------------------------------------------------
// bf16 MFMA GEMM, 128x64 tile, BK=32, 4 waves (2Mx2N, each 64x32 out).
// C(fp32 MxNb) = A(bf16 MxK) * Bt(bf16 NbxK)^T.  Dual-B via blockIdx.x.
// ---------------------------------------------------------------------------
__global__ __launch_bounds__(256) void gemm_mfma(
    const __hip_bfloat16* __restrict__ A,
    const __hip_bfloat16* __restrict__ Bt0, float* __restrict__ C0,
    const __hip_bfloat16* __restrict__ Bt1, float* __restrict__ C1,
    int Nb, int K, int ntiles_n)
{
    __shared__ __hip_bfloat16 As[128 * 32];   // 8 KB
    __shared__ __hip_bfloat16 Bs[64 * 32];    // 4 KB

    int t = threadIdx.x;
    int l = t & 63;
    int w = t >> 6;
    int wr = w >> 1, wc = w & 1;

    int bnt = blockIdx.x;
    const __hip_bfloat16* Bt = Bt0;
    float* C = C0;
    if (bnt >= ntiles_n) { Bt = Bt1; C = C1; bnt -= ntiles_n; }
    int bm = blockIdx.y * 128;
    int bn = bnt * 64;

    // staging addresses: thread t -> row t>>2, k-chunk (t&3)*8
    int srow = t >> 2;
    int skc  = (t & 3) * 8;
    const __hip_bfloat16* ga0 = A + (size_t)(bm + srow) * K + skc;
    const __hip_bfloat16* ga1 = A + (size_t)(bm + 64 + srow) * K + skc;
    const __hip_bfloat16* gb  = Bt + (size_t)(bn + srow) * K + skc;
    __hip_bfloat16* lA0 = &As[(t & ~63) * 8];
    __hip_bfloat16* lA1 = &As[2048 + (t & ~63) * 8];
    __hip_bfloat16* lB  = &Bs[(t & ~63) * 8];

    f32x4 acc[4][2] = {};

    int aro = (wr * 64 + (l & 15)) * 32 + (l >> 4) * 8;
    int bro = (wc * 32 + (l & 15)) * 32 + (l >> 4) * 8;

    for (int k0 = 0; k0 < K; k0 += 32) {
        GLOAD_LDS16(ga0 + k0, lA0);
        GLOAD_LDS16(ga1 + k0, lA1);
        GLOAD_LDS16(gb  + k0, lB);
        __syncthreads();

        short8 af[4], bf[2];
        #pragma unroll
        for (int m = 0; m < 4; ++m) af[m] = *(const short8*)&As[aro + m * 16 * 32];
        #pragma unroll
        for (int n = 0; n < 2; ++n) bf[n] = *(const short8*)&Bs[bro + n * 16 * 32];

        #pragma unroll
        for (int m = 0; m < 4; ++m)
            #pragma unroll
            for (int n = 0; n < 2; ++n)
                acc[m][n] = __builtin_amdgcn_mfma_f32_16x16x32_bf16(
                                af[m], bf[n], acc[m][n], 0, 0, 0);
        __syncthreads();
    }

    int crow = bm + wr * 64 + (l >> 4) * 4;
    int ccol = bn + wc * 32 + (l & 15);
    #pragma unroll
    for (int m = 0; m < 4; ++m)
        #pragma unroll
        for (int n = 0; n < 2; ++n)
            #pragma unroll
            for (int j = 0; j < 4; ++j)
                C[(size_t)(crow + m * 16 + j) * Nb + ccol + n * 16] = acc[m][n][j];
}

// ---------------------------------------------------------------------------
// Chunk-parallel banded attention, fused normalization; when the whole band
// fits one chunk (nch==1) the full epilogue is fused and Yb is written
// directly; otherwise the partial goes to Ypart.
// ---------------------------------------------------------------------------
__global__ __launch_bounds__(256) void attn_chunk_kernel(
    const float* __restrict__ qg, const float* __restrict__ kv,
    const float* __restrict__ log_window, const float* __restrict__ log_r,
    const float* __restrict__ log_hscale,
    float* __restrict__ Ypart, __hip_bfloat16* __restrict__ Yb)
{
    int bid = blockIdx.x;                 // h*(128*NCH_MAX) + tile*NCH_MAX + slot
    int h    = bid / (128 * NCH_MAX);
    int rem  = bid - h * (128 * NCH_MAX);
    int tile = rem / NCH_MAX;
    int slot = rem - tile * NCH_MAX;
    int i0 = tile * TI;
    int t = threadIdx.x;

    float w = expf(log_window[h]) + 1.f;
    float r = expf(log_r[h]) + 1.f;
    int dmax = (int)ceilf(w) - 1;         // <= 259
    int jstart = i0 - dmax; if (jstart < 0) jstart = 0;
    int nch = (i0 + TI - jstart + DC - 1) / DC;
    if (slot >= nch) return;
    int j0 = jstart + slot * DC;

    __shared__ float Q_lds[TI][16];
    __shared__ float K_lds[DC][16];
    __shared__ float V_lds[DC][DVH];
    __shared__ float att_lds[TI][68];
    __shared__ float soft_lds[288];

    const float PI = 3.14159265358979f;
    for (int d = t; d <= dmax; d += 256)
        soft_lds[d] = 0.5f * (cosf(PI * (float)d / w) + 1.f);

    // Q stage + normalize (32 rows, 4 lanes/row)
    if (t < TI * 4) {
        int iq = t >> 2, c = (t & 3) * 4;
        float4 qv = *(const float4*)(qg + (size_t)(i0 + iq) * QGN + h * QGW + c);
        float s = qv.x*qv.x + qv.y*qv.y + qv.z*qv.z + qv.w*qv.w;
        s += __shfl_xor(s, 1); s += __shfl_xor(s, 2);
        float inv = 1.f / fmaxf(sqrtf(s), 1e-12f);
        qv.x *= inv; qv.y *= inv; qv.z *= inv; qv.w *= inv;
        *(float4*)&Q_lds[iq][c] = qv;
    }
    // K stage + normalize (64 rows, 4 lanes/row)
    {
        int jr = t >> 2, c = (t & 3) * 4;
        int j = j0 + jr;
        float4 kx = make_float4(0.f, 0.f, 0.f, 0.f);
        if (j < N_TOK)
            kx = *(const float4*)(kv + (size_t)j * QGN + h * QGW + c);
        float s = kx.x*kx.x + kx.y*kx.y + kx.z*kx.z + kx.w*kx.w;
        s += __shfl_xor(s, 1); s += __shfl_xor(s, 2);
        float inv = 1.f / fmaxf(sqrtf(s), 1e-12f);
        kx.x *= inv; kx.y *= inv; kx.z *= inv; kx.w *= inv;
        *(float4*)&K_lds[jr][c] = kx;
    }
    // V stage + normalize (64 rows x 64, 16 lanes/row)
    #pragma unroll
    for (int kk = 0; kk < 4; ++kk) {
        int f = t + kk * 256;
        int jc = f >> 4, c = (f & 15) * 4;
        int j = j0 + jc;
        float4 vx = make_float4(0.f, 0.f, 0.f, 0.f);
        if (j < N_TOK)
            vx = *(const float4*)(kv + (size_t)j * QGN + h * QGW + DKQ + c);
        float s = vx.x*vx.x + vx.y*vx.y + vx.z*vx.z + vx.w*vx.w;
        s += __shfl_xor(s, 1); s += __shfl_xor(s, 2);
        s += __shfl_xor(s, 4); s += __shfl_xor(s, 8);
        float inv = 1.f / fmaxf(sqrtf(s), 1e-12f);
        vx.x *= inv; vx.y *= inv; vx.z *= inv; vx.w *= inv;
        *(float4*)&V_lds[jc][c] = vx;
    }
    __syncthreads();

    // scores: i = i0 + (t&31); this thread scores 8 j's
    int i_loc = t & 31;
    int jgrp  = t >> 5;
    int i_glob = i0 + i_loc;
    float q[16];
    #pragma unroll
    for (int c = 0; c < 16; ++c) q[c] = Q_lds[i_loc][c];

    #pragma unroll
    for (int jj = 0; jj < 8; ++jj) {
        int jc = jgrp * 8 + jj;
        int j = j0 + jc;
        int d = i_glob - j;
        float sim = 0.f;
        #pragma unroll
        for (int c4 = 0; c4 < 4; ++c4) {
            float4 kk4 = *(const float4*)&K_lds[jc][c4 * 4];
            sim += q[c4*4+0]*kk4.x + q[c4*4+1]*kk4.y
                 + q[c4*4+2]*kk4.z + q[c4*4+3]*kk4.w;
        }
        float a = fmaxf(1.f - r * (1.f - sim), 0.f);
        int dc = min(max(d, 0), dmax);
        bool valid = (d >= 0) && (d <= dmax);
        att_lds[i_loc][jc] = valid ? a * a * soft_lds[dc] : 0.f;
    }
    __syncthreads();

    // PV: wave wv, half ihalf -> 4 i's; lane pair dvp -> dv {2dvp, 2dvp+1}
    int wv = t >> 6, ihalf = (t >> 5) & 1, dvp = t & 31;
    int ib = wv * 8 + ihalf * 4;
    float acc[4][2] = {};

    #pragma unroll
    for (int g4 = 0; g4 < 16; ++g4) {
        int jc0 = g4 * 4;
        float4 am[4];
        #pragma unroll
        for (int m = 0; m < 4; ++m)
            am[m] = *(const float4*)&att_lds[ib + m][jc0];
        float2 v0 = *(const float2*)&V_lds[jc0 + 0][dvp * 2];
        float2 v1 = *(const float2*)&V_lds[jc0 + 1][dvp * 2];
        float2 v2 = *(const float2*)&V_lds[jc0 + 2][dvp * 2];
        float2 v3 = *(const float2*)&V_lds[jc0 + 3][dvp * 2];
        #pragma unroll
        for (int m = 0; m < 4; ++m) {
            acc[m][0] += am[m].x * v0.x + am[m].y * v1.x
                       + am[m].z * v2.x + am[m].w * v3.x;
            acc[m][1] += am[m].x * v0.y + am[m].y * v1.y
                       + am[m].z * v2.y + am[m].w * v3.y;
        }
    }

    if (nch == 1) {
        // full band in this chunk -> fused epilogue, write Yb directly
        float hs = expf(log_hscale[h]);
        #pragma unroll
        for (int m = 0; m < 4; ++m) {
            float ss = acc[m][0]*acc[m][0] + acc[m][1]*acc[m][1];
            #pragma unroll
            for (int off = 16; off; off >>= 1) ss += __shfl_xor(ss, off);
            float norm = sqrtf(ss);
            float scale = tanhf(norm) / fmaxf(norm, 1e-12f);
            int i = i0 + ib + m;
            float2 g2 = *(const float2*)(qg + (size_t)i * QGN + h * QGW + DKQ + dvp * 2);
            float gate0 = tanhf(g2.x / (1.f + expf(-g2.x)));
            float gate1 = tanhf(g2.y / (1.f + expf(-g2.y)));
            __hip_bfloat16 ob[2] = { __float2bfloat16(acc[m][0] * scale * gate0 * hs),
                                     __float2bfloat16(acc[m][1] * scale * gate1 * hs) };
            *(ushort2*)(Yb + (size_t)i * HD + h * DVH + dvp * 2) = *(const ushort2*)ob;
        }
    } else {
        #pragma unroll
        for (int m = 0; m < 4; ++m) {
            int i = i0 + ib + m;
            float2 st = make_float2(acc[m][0], acc[m][1]);
            *(float2*)(Ypart + ((size_t)slot * N_TOK + i) * HD + h * DVH + dvp * 2) = st;
        }
    }
}

// ---------------------------------------------------------------------------
// Epilogue for multi-chunk (h,i) only: sum partials, norm/tanh/gate/hscale.
// One wave per (h, i); 4 waves per block; nch==1 waves exit.
// ---------------------------------------------------------------------------
__global__ __launch_bounds__(256) void attn_epilogue_kernel(
    const float* __restrict__ Ypart, const float* __restrict__ qg,
    const float* __restrict__ log_window, const float* __restrict__ log_hscale,
    __hip_bfloat16* __restrict__ Y)
{
    int wv = threadIdx.x >> 6, lane = threadIdx.x & 63;
    int gid = blockIdx.x * 4 + wv;        // h*N_TOK + i
    int h = gid >> 12;
    int i = gid & (N_TOK - 1);

    float w  = expf(log_window[h]) + 1.f;
    int dmax = (int)ceilf(w) - 1;
    int i0 = i & ~(TI - 1);
    int jstart = i0 - dmax; if (jstart < 0) jstart = 0;
    int nch = (i0 + TI - jstart + DC - 1) / DC;
    if (nch < 2) return;                  // handled by fused path

    float hs = expf(log_hscale[h]);
    size_t base = (size_t)i * HD + h * DVH + lane;
    float a = 0.f;
    for (int c = 0; c < nch; ++c)
        a += Ypart[(size_t)c * N_TOK * HD + base];

    float g = qg[(size_t)i * QGN + h * QGW + DKQ + lane];
    float gate = tanhf(g / (1.f + expf(-g)));

    float ss = a * a;
    #pragma unroll
    for (int off = 32; off; off >>= 1) ss += __shfl_xor(ss, off);
    float norm = sqrtf(ss);
    float scale = tanhf(norm) / fmaxf(norm, 1e-12f);

    float o = a * scale * gate * hs;
    Y[(size_t)i * HD + h * DVH + lane] = __float2bfloat16(o);
}

// ---------------------------------------------------------------------------
extern "C" void kernel_launch(void* const* d_in, const int* in_sizes, int n_in,
                              void* d_out, int out_size, void* d_ws, size_t ws_size,
                              hipStream_t stream)
{
    const float* tokens     = (const float*)d_in[0];
    const float* w_qg       = (const float*)d_in[1];
    const float* w_kv       = (const float*)d_in[2];
    const float* w_out      = (const float*)d_in[3];
    const float* log_window = (const float*)d_in[4];
    const float* log_r      = (const float*)d_in[5];
    const float* log_hscale = (const float*)d_in[6];
    float* out = (float*)d_out;

    char* ws = (char*)d_ws;
    float* qg = (float*)ws;            ws += (size_t)N_TOK * QGN * 4;
    float* kv = (float*)ws;            ws += (size_t)N_TOK * QGN * 4;
    __hip_bfloat16* tokB  = (__hip_bfloat16*)ws; ws += (size_t)N_TOK * D_MODEL * 2;
    __hip_bfloat16* wqgT  = (__hip_bfloat16*)ws; ws += (size_t)QGN * D_MODEL * 2;
    __hip_bfloat16* wkvT  = (__hip_bfloat16*)ws; ws += (size_t)QGN * D_MODEL * 2;
    __hip_bfloat16* woutT = (__hip_bfloat16*)ws; ws += (size_t)D_MODEL * HD * 2;
    __hip_bfloat16* Yb    = (__hip_bfloat16*)ws; ws += (size_t)N_TOK * HD * 2;
    float* Ypart = (float*)ws;         ws += (size_t)NCH_MAX * N_TOK * HD * 4;

    // 0) pack
    pack_kernel<<<5888, 256, 0, stream>>>(tokens, w_qg, w_kv, w_out,
                                          tokB, wqgT, wkvT, woutT);
    // 1) qg / kv projection (dual-B, BN=64 -> 640 blocks)
    {
        dim3 grid(2 * (QGN / 64), N_TOK / 128);
        gemm_mfma<<<grid, 256, 0, stream>>>(tokB, wqgT, qg, wkvT, kv,
                                            QGN, D_MODEL, QGN / 64);
    }
    // 2) chunk-parallel attention (fused norm; fused epilogue when nch==1)
    attn_chunk_kernel<<<NHEAD * (N_TOK / TI) * NCH_MAX, 256, 0, stream>>>(
        qg, kv, log_window, log_r, log_hscale, Ypart, Yb);
    // 3) epilogue for multi-chunk rows
    attn_epilogue_kernel<<<NHEAD * N_TOK / 4, 256, 0, stream>>>(
        Ypart, qg, log_window, log_hscale, Yb);
    // 4) out = Y @ w_out (BN=64 -> 512 blocks)
    {
        dim3 grid(D_MODEL / 64, N_TOK / 128);
        gemm_mfma<<<grid, 256, 0, stream>>>(Yb, woutT, out, woutT, out,
                                            D_MODEL, HD, D_MODEL / 64);
    }
}